// Round 3
// baseline (444.763 us; speedup 1.0000x reference)
//
#include <hip/hip_runtime.h>
#include <stdint.h>

#define DEVI __device__ __forceinline__

using bf16x8 = __attribute__((ext_vector_type(8))) __bf16;
using f32x4  = __attribute__((ext_vector_type(4))) float;

DEVI ushort f2bf(float f){
  uint32_t u = __float_as_uint(f);
  uint32_t r = u + 0x7fffu + ((u >> 16) & 1u);   // RNE
  return (ushort)(r >> 16);
}
DEVI float bf2f(ushort h){ return __uint_as_float(((uint32_t)h) << 16); }

// async 16B global -> LDS (wave-uniform LDS base; lane lands at base + lane*16)
DEVI void async16(const ushort* g, ushort* l, int lbyte) {
  __builtin_amdgcn_global_load_lds(
      (const __attribute__((address_space(1))) uint32_t*)g,
      (__attribute__((address_space(3))) uint32_t*)((char*)l + lbyte),
      16, 0, 0);
}

// ---------------------------------------------------------------------------
// Segmented mega-GEMM. Each dispatch carries up to 3 segments; flat blockIdx
// ranges select the segment. NT GEMM: D[m,n] = sum_k A[m,k]*B[n,k].
// Tile 128x128, BK=64 staged as two 128x32 LDS sub-tiles (halves barriers,
// keeps m97 conflict pattern). flags: 1=relu 2=out_bf16 4=src_bf16 8=src_f32
// 16=dual(2nd pass A+A2off/B+B2off, combine relu(p0)+relu(p1)) 32=softmax.
// ---------------------------------------------------------------------------
struct Seg {
  const ushort* A; const ushort* B; const void* Src; void* O;
  long long sA, sB, sS, sO;
  int lda, ldb, ldS, ldc;
  int K, nbx, nbxy, flags;
  long long A2off, B2off;
};

__global__ __launch_bounds__(256, 3)
void mega(Seg s0, Seg s1, Seg s2, int n0, int n01)
{
  extern __shared__ __align__(16) ushort lds[];
  int bid = blockIdx.x;
  Seg s;
  if (bid < n0) { s = s0; }
  else if (bid < n01) { s = s1; bid -= n0; }
  else { s = s2; bid -= n01; }

  const int t = threadIdx.x;

  if (s.flags & 32) {   // ---- softmax over 256-wide rows, fp32 -> bf16 ----
    const int row  = bid*4 + (t >> 6);
    const int lane = t & 63;
    const float* in = (const float*)s.A;
    ushort* outp = (ushort*)s.O;
    const float4 v = ((const float4*)(in + (long long)row*256))[lane];
    float m = fmaxf(fmaxf(v.x, v.y), fmaxf(v.z, v.w));
    #pragma unroll
    for (int off = 32; off; off >>= 1) m = fmaxf(m, __shfl_xor(m, off, 64));
    float e0 = __expf(v.x - m), e1 = __expf(v.y - m), e2 = __expf(v.z - m), e3 = __expf(v.w - m);
    float sum = e0 + e1 + e2 + e3;
    #pragma unroll
    for (int off = 32; off; off >>= 1) sum += __shfl_xor(sum, off, 64);
    const float inv = 1.0f / sum;
    ushort4 o;
    o.x = f2bf(e0*inv); o.y = f2bf(e1*inv); o.z = f2bf(e2*inv); o.w = f2bf(e3*inv);
    ((ushort4*)(outp + (long long)row*256))[lane] = o;
    return;
  }

  ushort* lA0 = lds;        ushort* lA1 = lds + 4096;
  ushort* lB0 = lds + 8192; ushort* lB1 = lds + 12288;

  const int z  = bid / s.nbxy;
  const int rz = bid % s.nbxy;
  const int bx = rz % s.nbx, by = rz / s.nbx;

  const int lane = t & 63, wave = t >> 6;
  const int wm = (wave >> 1)*64, wn = (wave & 1)*64;
  const int lr = lane & 15, lq = lane >> 4;

  const int r0 = t >> 2, c0 = (t & 3)*8;
  const int lb0 = __builtin_amdgcn_readfirstlane((t & 192) * 16);
  const int lb1 = lb0 + 4096;

  f32x4 acc[4][4] = {};
  uint pk[4][4][2];
  const int npass = (s.flags & 16) ? 2 : 1;

  for (int p = 0; p < npass; ++p) {
    const ushort* Ab = s.A + (p ? s.A2off : 0) + (long long)z*s.sA + (long long)by*128*s.lda;
    const ushort* Bb = s.B + (p ? s.B2off : 0) + (long long)z*s.sB + (long long)bx*128*s.ldb;
    const ushort* pa = Ab + (long long)r0*s.lda + c0;
    const ushort* pb = Bb + (long long)r0*s.ldb + c0;
    const long long a64 = 64ll*s.lda, b64 = 64ll*s.ldb;

    for (int k0 = 0; k0 < s.K; k0 += 64) {
      __syncthreads();
      async16(pa + k0,            lA0, lb0);
      async16(pa + a64 + k0,      lA0, lb1);
      async16(pa + k0 + 32,       lA1, lb0);
      async16(pa + a64 + k0 + 32, lA1, lb1);
      async16(pb + k0,            lB0, lb0);
      async16(pb + b64 + k0,      lB0, lb1);
      async16(pb + k0 + 32,       lB1, lb0);
      async16(pb + b64 + k0 + 32, lB1, lb1);
      __syncthreads();
      {
        bf16x8 af[4], bfr[4];
        #pragma unroll
        for (int i = 0; i < 4; i++) {
          af[i]  = *(const bf16x8*)&lA0[(wm + i*16 + lr)*32 + lq*8];
          bfr[i] = *(const bf16x8*)&lB0[(wn + i*16 + lr)*32 + lq*8];
        }
        #pragma unroll
        for (int i = 0; i < 4; i++)
          #pragma unroll
          for (int j = 0; j < 4; j++)
            acc[i][j] = __builtin_amdgcn_mfma_f32_16x16x32_bf16(af[i], bfr[j], acc[i][j], 0, 0, 0);
      }
      {
        bf16x8 af[4], bfr[4];
        #pragma unroll
        for (int i = 0; i < 4; i++) {
          af[i]  = *(const bf16x8*)&lA1[(wm + i*16 + lr)*32 + lq*8];
          bfr[i] = *(const bf16x8*)&lB1[(wn + i*16 + lr)*32 + lq*8];
        }
        #pragma unroll
        for (int i = 0; i < 4; i++)
          #pragma unroll
          for (int j = 0; j < 4; j++)
            acc[i][j] = __builtin_amdgcn_mfma_f32_16x16x32_bf16(af[i], bfr[j], acc[i][j], 0, 0, 0);
      }
    }

    if (p == 0 && npass == 2) {   // stash relu(pass0) as packed bf16, reset acc
      #pragma unroll
      for (int i = 0; i < 4; i++)
        #pragma unroll
        for (int j = 0; j < 4; j++) {
          pk[i][j][0] = (uint)f2bf(fmaxf(acc[i][j][0], 0.0f)) | ((uint)f2bf(fmaxf(acc[i][j][1], 0.0f)) << 16);
          pk[i][j][1] = (uint)f2bf(fmaxf(acc[i][j][2], 0.0f)) | ((uint)f2bf(fmaxf(acc[i][j][3], 0.0f)) << 16);
          acc[i][j] = (f32x4){0.f, 0.f, 0.f, 0.f};
        }
    }
  }

  // epilogue: D row = (lane>>4)*4 + reg, col = lane&15
  const int rowb = by*128 + wm + lq*4;
  const int colb = bx*128 + wn + lr;
  const int fl = s.flags;
  #pragma unroll
  for (int i = 0; i < 4; i++) {
    #pragma unroll
    for (int j = 0; j < 4; j++) {
      const int col = colb + j*16;
      #pragma unroll
      for (int r = 0; r < 4; r++) {
        const int row = rowb + i*16 + r;
        float v = acc[i][j][r];
        if (fl & 1)  v = fmaxf(v, 0.0f);
        if (fl & 16) v += bf2f((ushort)(pk[i][j][r >> 1] >> (16*(r & 1))));
        if (fl & 4)  v += bf2f(((const ushort*)s.Src)[(long long)z*s.sS + (long long)row*s.ldS + col]);
        if (fl & 8)  v += ((const float*)s.Src)[(long long)z*s.sS + (long long)row*s.ldS + col];
        if (fl & 2)
          ((ushort*)s.O)[(long long)z*s.sO + (long long)row*s.ldc + col] = f2bf(v);
        else
          ((float*)s.O)[(long long)z*s.sO + (long long)row*s.ldc + col] = v;
      }
    }
  }
}

// ---------------------------------------------------------------------------
// fused prep: [0,8192) cast f -> bf16 ; [8192,11008) 11 weight transposes ;
// [11008,15104) adj -> adj/adjT bf16
// ---------------------------------------------------------------------------
struct P11 { const float* p[11]; };

__global__ void prep(const float* __restrict__ F, ushort* __restrict__ FB,
                     P11 ps, ushort* __restrict__ WT,
                     const float* __restrict__ ADJ, ushort* __restrict__ AB,
                     ushort* __restrict__ ATB)
{
  __shared__ float tile[32][33];
  const int b = blockIdx.x, t = threadIdx.x;
  if (b < 8192) {                       // cast f (8.4M elems, float4/thread)
    const int i = b*256 + t;
    const float4 v = ((const float4*)F)[i];
    ushort4 o; o.x = f2bf(v.x); o.y = f2bf(v.y); o.z = f2bf(v.z); o.w = f2bf(v.w);
    ((ushort4*)FB)[i] = o;
  } else if (b < 11008) {               // W (512x512) -> W^T bf16
    const int q = b - 8192;
    const int wdx = q >> 8, tl = q & 255;
    const int bo = (tl & 15)*32, bk = (tl >> 4)*32;
    const int tx = t & 31, ty = t >> 5;
    const float* in = ps.p[wdx];
    ushort* o = WT + (long long)wdx*262144;
    #pragma unroll
    for (int r = 0; r < 32; r += 8) tile[ty+r][tx] = in[(long long)(bk+ty+r)*512 + bo+tx];
    __syncthreads();
    #pragma unroll
    for (int r = 0; r < 32; r += 8) o[(long long)(bo+ty+r)*512 + bk+tx] = f2bf(tile[tx][ty+r]);
  } else {                              // adj -> adj bf16 + adjT bf16
    const int q = b - 11008;
    const long long base = (long long)(q >> 6)*65536;
    const int bi = ((q >> 3) & 7)*32, bj = (q & 7)*32;
    const int tx = t & 31, ty = t >> 5;
    #pragma unroll
    for (int r = 0; r < 32; r += 8) {
      const float v = ADJ[base + (long long)(bi+ty+r)*256 + bj+tx];
      tile[ty+r][tx] = v;
      AB[base + (long long)(bi+ty+r)*256 + bj+tx] = f2bf(v);
    }
    __syncthreads();
    #pragma unroll
    for (int r = 0; r < 32; r += 8)
      ATB[base + (long long)(bj+ty+r)*256 + bi+tx] = f2bf(tile[tx][ty+r]);
  }
}

// ---------------------------------------------------------------------------
extern "C" void kernel_launch(void* const* d_in, const int* in_sizes, int n_in,
                              void* d_out, int out_size, void* d_ws, size_t ws_size,
                              hipStream_t stream)
{
  (void)in_sizes; (void)n_in; (void)out_size;
  const float* F   = (const float*)d_in[0];
  const float* ADJ = (const float*)d_in[2];

  uint8_t* w = (uint8_t*)d_ws;
  size_t off = 0;
  auto alloc = [&](size_t bytes) -> void* { void* p = w + off; off += (bytes + 255) & ~(size_t)255; return p; };

  const long long SL = 262144;                   // 512x512 bf16 elements
  ushort* WT   = (ushort*)alloc(11*524288);      // 0:Wst1 1:Wst1b 2:Wst2 3:Wst2b 4:Wst3 5:Wst3b 6-8:Wsim1-3 9:Wse1T 10:Wse2T
  ushort* WMT  = (ushort*)alloc(524288);         // Wmid^T bf16
  ushort* FB   = (ushort*)alloc(16777216);       // f bf16 (B,N,C)
  ushort* ADJB = (ushort*)alloc(8388608);
  ushort* ADJT = (ushort*)alloc(8388608);
  ushort* TB   = (ushort*)alloc(16777216);       // T = f@Wmid bf16
  float*  SC32 = (float*)alloc(16777216);        // Sc fp32 (B,N,N)
  ushort* Sb   = (ushort*)alloc(8388608);        // S bf16
  ushort* YTB  = (ushort*)alloc(33554432);       // stacked st YT (B,1024,256)
  ushort* SY   = (ushort*)alloc(16777216);       // sim YT (B,512,256)
  ushort* Gb   = (ushort*)alloc(16777216);       // sim hidden
  ushort* Hb   = (ushort*)alloc(16777216);       // st hidden / st result
  if (off > ws_size) return;

  const long long sNC = 131072, sNN = 65536, sYT = 262144, sSY = 131072;

  auto mk = [](const void* A, long long sA, int lda, const void* B, long long sB, int ldb,
               const void* Src, long long sS, int ldS, void* O, long long sO, int ldc,
               int K, int M, int Nn, int flags, long long A2off, long long B2off) -> Seg {
    Seg s; s.A = (const ushort*)A; s.B = (const ushort*)B; s.Src = Src; s.O = O;
    s.sA = sA; s.sB = sB; s.sS = sS; s.sO = sO;
    s.lda = lda; s.ldb = ldb; s.ldS = ldS; s.ldc = ldc;
    s.K = K; s.nbx = Nn/128; s.nbxy = (Nn/128)*(M/128); s.flags = flags;
    s.A2off = A2off; s.B2off = B2off; return s;
  };
  auto L1 = [&](const Seg& a, int na) { mega<<<na, 256, 32768, stream>>>(a, a, a, na, na); };
  auto L2 = [&](const Seg& a, int na, const Seg& b, int nb) {
    mega<<<na+nb, 256, 32768, stream>>>(a, b, b, na, na+nb); };
  auto L3 = [&](const Seg& a, int na, const Seg& b, int nb, const Seg& c, int nc) {
    mega<<<na+nb+nc, 256, 32768, stream>>>(a, b, c, na, na+nb); };

  // ---- D1: fused prep ----
  P11 ps;
  ps.p[0] = (const float*)d_in[5];  ps.p[1] = (const float*)d_in[8];
  ps.p[2] = (const float*)d_in[6];  ps.p[3] = (const float*)d_in[9];
  ps.p[4] = (const float*)d_in[7];  ps.p[5] = (const float*)d_in[10];
  ps.p[6] = (const float*)d_in[11]; ps.p[7] = (const float*)d_in[12];
  ps.p[8] = (const float*)d_in[13];
  ps.p[9] = (const float*)d_in[3];  ps.p[10] = (const float*)d_in[4];
  prep<<<15104, 256, 0, stream>>>(F, FB, ps, WT, ADJ, ADJB, ADJT);

  const long long dA = (long long)(ADJT - ADJB);

  Seg Wmid = mk(WT+10*SL,0,512, WT+9*SL,0,512, nullptr,0,0, WMT,0,512, 512, 512,512, 2, 0,0);
  Seg Z1   = mk(WT+0*SL,0,512, FB,sNC,512, nullptr,0,0, YTB,sYT,256, 512, 1024,256, 2, 0,0);
  Seg Y1   = mk(WT+6*SL,0,512, FB,sNC,512, nullptr,0,0, SY,sSY,256, 512, 512,256, 2, 0,0);
  Seg Tsg  = mk(FB,sNC,512, WMT,0,512, nullptr,0,0, TB,sNC,512, 512, 256,512, 2, 0,0);
  Seg H1   = mk(ADJB,sNN,256, YTB,sYT,256, nullptr,0,0, Hb,sNC,512, 256, 256,512, 1|2|16, dA,131072);
  Seg Sc   = mk(TB,sNC,512, FB,sNC,512, nullptr,0,0, SC32,sNN,256, 512, 256,256, 0, 0,0);
  Seg Z2   = mk(WT+2*SL,0,512, Hb,sNC,512, nullptr,0,0, YTB,sYT,256, 512, 1024,256, 2, 0,0);
  Seg SM; SM.A = (const ushort*)SC32; SM.O = Sb; SM.flags = 32;
  SM.B = nullptr; SM.Src = nullptr; SM.sA = SM.sB = SM.sS = SM.sO = 0;
  SM.lda = SM.ldb = SM.ldS = SM.ldc = 0; SM.K = 0; SM.nbx = SM.nbxy = 1; SM.A2off = SM.B2off = 0;
  Seg H2   = H1;   // B=YTB (Z2 contents), O=Hb
  Seg G1   = mk(Sb,sNN,256, SY,sSY,256, nullptr,0,0, Gb,sNC,512, 256, 256,512, 1|2, 0,0);
  Seg Z3   = mk(WT+4*SL,0,512, Hb,sNC,512, nullptr,0,0, YTB,sYT,256, 512, 1024,256, 2, 0,0);
  Seg Y2   = mk(WT+7*SL,0,512, Gb,sNC,512, nullptr,0,0, SY,sSY,256, 512, 512,256, 2, 0,0);
  Seg H3   = H1;
  Seg G2   = G1;   // B=SY (Y2), O=Gb
  Seg Y3   = mk(WT+8*SL,0,512, Gb,sNC,512, nullptr,0,0, SY,sSY,256, 512, 512,256, 2, 0,0);
  Seg Fin  = mk(Sb,sNN,256, SY,sSY,256, Hb,sNC,512, d_out,sNC,512, 256, 256,512, 1|4, 0,0);

  // ---- schedule: sim chain (T,Sc,SM,G1,Y2,G2,Y3,Fin) || st chain (Z1,H1,Z2,H2,Z3,H3)
  L3(Wmid,16, Z1,1024, Y1,512);   // D2
  L2(Tsg,512, H1,512);            // D3
  L2(Sc,256,  Z2,1024);           // D4
  L2(SM,4096, H2,512);            // D5
  L2(G1,512,  Z3,1024);           // D6
  L2(Y2,512,  H3,512);            // D7
  L1(G2,512);                     // D8
  L1(Y3,512);                     // D9
  L1(Fin,512);                    // D10
}